// Round 7
// baseline (118.509 us; speedup 1.0000x reference)
//
#include <hip/hip_runtime.h>
#include <hip/hip_bf16.h>

// Ensemble SRN: 8 sub-models (2x2x2 octants), MLP 3->128->128->128->1, ReLU.
// R7: 2-kernel pipeline, register-resident weights, TILE=128 main.
//  node 1: srn_scatter — classify/normalize points into per-model float4
//          {xn0,xn1,xn2,pid} segments (block 0 zeroes cursors, flag-spin).
//  node 2: srn_main — grid 64x8 (512 blocks, 2/CU); each wave holds its
//          32-col B-fragments of W1 AND W2 in registers (64 VGPRs), loaded
//          once per block from fp32 d_in. Per 128-point tile: layer0 VALU,
//          2 MFMA gemms (64 MFMA/wave each), layer3 dot.
// Lesson bank: grid.sync ~200us @G=1024 (R4 — kernel boundaries are the
// cheap grid barrier); per-tile global weight reads = 134+ MB HBM stream
// after ws poison (R5 — keep weights in regs, load from d_in not ws).
// Harness floor ~100us: 268MB ws poison fill (40us @83% HBM) + restores.
// ws: [0,64)           cursors[8] + ready flag
//     [64, 64+16*N*8)  xn segments: float4 per point, per-model capacity N

#define HDIM 128
#define LDSH 136      // padded LDS stride (bf16): 272B rows -> 2-way alias (free)
#define TILE 128
#define NMODEL 8
#define GB 64         // blocks per model; grid 512 = 2 blocks/CU
#define SCAT_PPB 512
#define RDY_MAGIC 0x5AFE5AFE

typedef __bf16 bf16x8 __attribute__((ext_vector_type(8)));
typedef __bf16 bf16x4 __attribute__((ext_vector_type(4)));
typedef float  f32x4  __attribute__((ext_vector_type(4)));

__device__ __forceinline__ int model_of(float x0, float x1, float x2) {
  // match reference: u=(x+1)/(2+1e-6); cell=int(u_flipped*2); idx=c0+2c1+4c2
  const float den = 2.000001f;
  float u0 = (x0 + 1.0f) / den;
  float u1 = (x1 + 1.0f) / den;
  float u2 = (x2 + 1.0f) / den;
  int c0 = (int)(u2 * 2.0f);
  int c1 = (int)(u1 * 2.0f);
  int c2 = (int)(u0 * 2.0f);
  return c0 + (c1 << 1) + (c2 << 2);
}

// ---------- node 1: classify + normalize + scatter (validated R6) ----------
__global__ __launch_bounds__(256)
void srn_scatter(const float* __restrict__ x,
                 const float* __restrict__ mins, const float* __restrict__ maxs,
                 int* __restrict__ cursors, f32x4* __restrict__ xn, int N)
{
  __shared__ int lc[NMODEL], lb[NMODEL];
  const int b   = blockIdx.x;
  const int tid = threadIdx.x;
  if (tid < NMODEL) lc[tid] = 0;
  __syncthreads();

  const int base = b * SCAT_PPB;
  int ids[2], rs[2];
  float px[2][3];
  #pragma unroll
  for (int it = 0; it < 2; ++it) {
    const int i = base + it * 256 + tid;
    ids[it] = -1;
    if (i < N) {
      px[it][0] = x[3*i]; px[it][1] = x[3*i+1]; px[it][2] = x[3*i+2];
      ids[it] = model_of(px[it][0], px[it][1], px[it][2]);
      rs[it] = atomicAdd(&lc[ids[it]], 1);
    }
  }
  __syncthreads();

  // block 0 zeroes the poisoned cursors, then publishes the ready flag;
  // all other blocks spin (grid = N/512 = 256 blocks -> all co-resident).
  if (b == 0) {
    if (tid < NMODEL) atomicExch(&cursors[tid], 0);
    __threadfence();
    if (tid == 0) atomicExch(&cursors[NMODEL], RDY_MAGIC);
  } else if (tid == 0) {
    while (atomicCAS(&cursors[NMODEL], RDY_MAGIC, RDY_MAGIC) != RDY_MAGIC) {
      __builtin_amdgcn_s_sleep(8);
    }
  }
  __syncthreads();
  if (tid < NMODEL) lb[tid] = lc[tid] ? atomicAdd(&cursors[tid], lc[tid]) : 0;
  __syncthreads();

  #pragma unroll
  for (int it = 0; it < 2; ++it) {
    if (ids[it] >= 0) {
      const int m = ids[it];
      const float mn0 = mins[3*m], mn1 = mins[3*m+1], mn2 = mins[3*m+2];
      const float mx0 = maxs[3*m], mx1 = maxs[3*m+1], mx2 = maxs[3*m+2];
      f32x4 v;
      v[0] = -1.0f + 2.0f * (px[it][0] - mn0) / (mx0 - mn0);
      v[1] = -1.0f + 2.0f * (px[it][1] - mn1) / (mx1 - mn1);
      v[2] = -1.0f + 2.0f * (px[it][2] - mn2) / (mx2 - mn2);
      v[3] = __int_as_float(base + it * 256 + tid);
      xn[(size_t)m * N + lb[m] + rs[it]] = v;
    }
  }
}

// ---------- GEMM layer with register-resident B, 128-row tile ----------
// hOut = relu(hIn @ W + b); wave owns cols [n0, n0+32), 8 row-tiles.
__device__ __forceinline__ void gemm_reg(const __bf16* __restrict__ hIn,
                                         __bf16* __restrict__ hOut,
                                         const bf16x8 (&wr)[4][2],
                                         const float* __restrict__ biasS,
                                         int n0, int l16, int quad)
{
  f32x4 acc[8][2] = {};
  #pragma unroll
  for (int kk = 0; kk < 4; ++kk) {
    const int kOff = kk * 32 + quad * 8;
    #pragma unroll
    for (int r = 0; r < 8; ++r) {
      bf16x8 av = *(const bf16x8*)(hIn + (r * 16 + l16) * LDSH + kOff);
      acc[r][0] = __builtin_amdgcn_mfma_f32_16x16x32_bf16(av, wr[kk][0], acc[r][0], 0, 0, 0);
      acc[r][1] = __builtin_amdgcn_mfma_f32_16x16x32_bf16(av, wr[kk][1], acc[r][1], 0, 0, 0);
    }
  }
  const float bv0 = biasS[n0 + l16];
  const float bv1 = biasS[n0 + 16 + l16];
  #pragma unroll
  for (int r = 0; r < 8; ++r) {
    #pragma unroll
    for (int c = 0; c < 2; ++c) {
      const int n = n0 + c * 16 + l16;
      const float bb = c ? bv1 : bv0;
      #pragma unroll
      for (int i = 0; i < 4; ++i) {
        const int row = r * 16 + quad * 4 + i;   // C/D: col=lane&15, row=quad*4+reg
        float v = acc[r][c][i] + bb;
        hOut[row * LDSH + n] = (__bf16)fmaxf(v, 0.0f);
      }
    }
  }
}

// ---------- node 2: per-model 128-point-tile MFMA MLP, weights in regs ----------
__global__ __launch_bounds__(256, 2)
void srn_main(const float* __restrict__ W0, const float* __restrict__ b0,
              const float* __restrict__ W1, const float* __restrict__ b1,
              const float* __restrict__ W2, const float* __restrict__ b2,
              const float* __restrict__ W3, const float* __restrict__ b3,
              const int* __restrict__ cursors, const f32x4* __restrict__ xn,
              float* __restrict__ out, int N)
{
  __shared__ __align__(16) __bf16 hA[TILE * LDSH];
  __shared__ __align__(16) __bf16 hB[TILE * LDSH];
  __shared__ float xs[TILE][3];
  __shared__ int   pid[TILE];
  __shared__ float w0s[3 * HDIM];
  __shared__ float b0s[HDIM], b1s[HDIM], b2s[HDIM], w3s[HDIM];

  const int m    = blockIdx.y;
  const int tid  = threadIdx.x;
  const int lane = tid & 63;
  const int wave = tid >> 6;
  const int l16  = lane & 15;
  const int quad = lane >> 4;
  const int n0   = wave * 32;

  // stage small per-model vectors in LDS (once per block)
  if (tid < HDIM) {
    const float* W0m = W0 + m * 3 * HDIM;
    w0s[tid]          = W0m[tid];
    w0s[HDIM + tid]   = W0m[HDIM + tid];
    w0s[2*HDIM + tid] = W0m[2*HDIM + tid];
    b0s[tid] = b0[m * HDIM + tid];
    b1s[tid] = b1[m * HDIM + tid];
    b2s[tid] = b2[m * HDIM + tid];
    w3s[tid] = W3[m * HDIM + tid];
  }

  // preload this wave's B-fragments of W1 and W2 (fp32 [k][n] -> bf16 regs).
  const float* W1m = W1 + m * HDIM * HDIM;
  const float* W2m = W2 + m * HDIM * HDIM;
  bf16x8 w1r[4][2], w2r[4][2];
  #pragma unroll
  for (int kk = 0; kk < 4; ++kk) {
    #pragma unroll
    for (int c = 0; c < 2; ++c) {
      const int off = (kk * 32 + quad * 8) * HDIM + n0 + c * 16 + l16;
      bf16x8 v1, v2;
      #pragma unroll
      for (int u = 0; u < 8; ++u) {
        v1[u] = (__bf16)W1m[off + u * HDIM];
        v2[u] = (__bf16)W2m[off + u * HDIM];
      }
      w1r[kk][c] = v1;
      w2r[kk][c] = v2;
    }
  }

  const int cnt = cursors[m];
  const f32x4* xnSeg = xn + (size_t)m * N;
  const float b3v = b3[m];
  __syncthreads();

  for (int tile = blockIdx.x; tile * TILE < cnt; tile += GB) {
    const int base = tile * TILE;
    const int npts = min(TILE, cnt - base);

    if (tid < TILE) {
      f32x4 v = xnSeg[base + tid];          // coalesced 16B/lane
      if (tid < npts) {
        pid[tid] = __float_as_int(v[3]);
        xs[tid][0] = v[0]; xs[tid][1] = v[1]; xs[tid][2] = v[2];
      } else {
        pid[tid] = -1;
        xs[tid][0] = 0.0f; xs[tid][1] = 0.0f; xs[tid][2] = 0.0f;
      }
    }
    __syncthreads();

    // layer 0: fp32 VALU, K=3 -> hA bf16 (1 point x 64 cols per thread)
    {
      const int p  = tid & 127;
      const int j0 = (tid >> 7) * 64;
      const float xv0 = xs[p][0], xv1 = xs[p][1], xv2 = xs[p][2];
      #pragma unroll
      for (int j = j0; j < j0 + 64; j += 4) {
        bf16x4 pk;
        #pragma unroll
        for (int u = 0; u < 4; ++u) {
          float v = b0s[j+u] + xv0 * w0s[j+u] + xv1 * w0s[HDIM + j+u] + xv2 * w0s[2*HDIM + j+u];
          pk[u] = (__bf16)fmaxf(v, 0.0f);
        }
        *(bf16x4*)(hA + p * LDSH + j) = pk;
      }
    }
    __syncthreads();

    gemm_reg(hA, hB, w1r, b1s, n0, l16, quad);   // layer 1
    __syncthreads();
    gemm_reg(hB, hA, w2r, b2s, n0, l16, quad);   // layer 2
    __syncthreads();

    // layer 3: dot(h2, w3), 2 lanes/point
    {
      const int p    = tid >> 1;
      const int part = tid & 1;
      float s = 0.0f;
      #pragma unroll
      for (int kk = 0; kk < 8; ++kk) {
        bf16x8 hv = *(const bf16x8*)(hA + p * LDSH + part * 64 + kk * 8);
        const float* wp = w3s + part * 64 + kk * 8;
        #pragma unroll
        for (int u = 0; u < 8; ++u) s += (float)hv[u] * wp[u];
      }
      s += __shfl_xor(s, 1);
      if (part == 0 && p < npts) out[pid[p]] = s + b3v;
    }
    __syncthreads();
  }
}

extern "C" void kernel_launch(void* const* d_in, const int* in_sizes, int n_in,
                              void* d_out, int out_size, void* d_ws, size_t ws_size,
                              hipStream_t stream)
{
  const float* x    = (const float*)d_in[0];
  const float* W0   = (const float*)d_in[1];
  const float* b0   = (const float*)d_in[2];
  const float* W1   = (const float*)d_in[3];
  const float* b1   = (const float*)d_in[4];
  const float* W2   = (const float*)d_in[5];
  const float* b2   = (const float*)d_in[6];
  const float* W3   = (const float*)d_in[7];
  const float* b3   = (const float*)d_in[8];
  const float* mins = (const float*)d_in[9];
  const float* maxs = (const float*)d_in[10];
  float* out = (float*)d_out;
  int N = in_sizes[0] / 3;

  char* ws = (char*)d_ws;
  int*   cursors = (int*)ws;            // [0,64): cursors[8] + ready flag
  f32x4* xn      = (f32x4*)(ws + 64);   // 8 segments x N float4

  const int sb = (N + SCAT_PPB - 1) / SCAT_PPB;
  srn_scatter<<<dim3(sb), dim3(256), 0, stream>>>(x, mins, maxs, cursors, xn, N);
  srn_main<<<dim3(GB, NMODEL), dim3(256), 0, stream>>>(
      W0, b0, W1, b1, W2, b2, W3, b3, cursors, xn, out, N);
}